// Round 9
// baseline (393.052 us; speedup 1.0000x reference)
//
#include <hip/hip_runtime.h>
#include <math.h>

#define NSTUFF 6
#define NCLS   10          // N_STUFF + N_THING
#define NBOX   32
#define NTHING 4
#define RR     28
#define HH     768
#define WW     704
#define NPIX   (HH * WW)   // 540672
#define BB     2
#define LL     (1 + NSTUFF + NBOX)   // 39
#define NEGV   (-100.0f)

// Tile 64x16, 1056 blocks. History:
//   R6:  256 thr / 4 px = 108.6 us end-to-end
//   R7:  4224 blocks REGRESSED (per-block fixed cost)
//   R8/R10: box-outer restructure REGRESSED — VALU never the bottleneck
//   R12: 512 thr / 2 px = 105.2 (WIN); R13: 1024 thr / 1 px = 104.0 (WIN)
//   R14: pipeline via struct/lambdas REGRESSED (promote-alloca -> LDS)
//   R15: pipeline via named scalars = 103.8 (kept; lever spent)
//   R16 (this): REMOVE the memset dispatch. counts-atomics -> per-block
//        partials (full overwrite of poisoned ws, no zeroing) + ticket in
//        out's po_iscrowd region ((old+1)%528==0 winner test is start-value
//        agnostic -> poison/replay-safe) + last-block reduction computes the
//        LUT once into ws. k_relabel becomes a pure remap. Evidence: the
//        2.6 KB memset showed up as a 43 us fillBufferAligned dispatch (R3
//        trace); non-kernel overhead ~30 us/iter across 5 clean runs.
#define TW 64
#define TH 16
#define TILES_X (WW / TW)            // 11
#define TILES_Y (HH / TH)            // 48
#define NTILES  (TILES_X * TILES_Y)  // 528 per batch
#define NHIST   (NBOX * NCLS + NSTUFF)  // 326
#define NHP     328                  // padded stride (16B multiple)
#define NTHR    1024

__device__ __forceinline__ float sigmoidf_(float x) {
    return 1.0f / (1.0f + expf(-x));
}

// ---------------------------------------------------------------------------
// K1: tiled fused logits + argmax + histograms. 1 px/thread; 10 independent
// scalar sem loads (64x4B coalesced), one latency round. Per-tile box cull
// in-register by wave 0. Box loop is a depth-2 software pipeline in named
// scalar registers (R15). Winner index (0..37) stored as a byte.
// Tail: per-block hist -> partials (overwrite), ticket atomicAdd in out's
// po_iscrowd slot, last block per batch reduces partials + computes LUT.
// Sequential-argmax semantics preserved via the gap rule (skipped boxes
// contribute exactly -0.0f; only the first box of a skipped run can win, and
// only while bv < 0; -0.0f < 0.0f is false so a claim happens at most once
// per run).
// ---------------------------------------------------------------------------
__global__ __launch_bounds__(NTHR, 4) void k_fuse(
    const float* __restrict__ sem,   // [B][10][H][W]
    const float* __restrict__ roi,   // [B][32][4][28][28]
    const float* __restrict__ bbx,   // [B][32][4]
    const int*   __restrict__ cls,   // [B][32]
    unsigned char* __restrict__ pred8, // ws region, [B][H][W] bytes
    int*         __restrict__ partials, // ws region, [B][528][NHP]
    int*         __restrict__ lutws,    // ws region, [B][128]
    int*         __restrict__ out)      // ticket lives in po_iscrowd region
{
    const int b = blockIdx.y;
    __shared__ int   sh_y0[NBOX], sh_x0[NBOX], sh_yme[NBOX], sh_xme[NBOX];
    __shared__ int   sh_yie[NBOX], sh_xie[NBOX], sh_moff[NBOX], sh_cls[NBOX];
    __shared__ float sh_y0f[NBOX], sh_x0f[NBOX], sh_sy[NBOX], sh_sx[NBOX];
    __shared__ int   sh_list[NBOX];
    __shared__ int   sh_nbox;
    __shared__ int   sh_cnt[NHIST];
    __shared__ int   sh_old;
    __shared__ int   w_sh[NSTUFF], w_ih[NBOX], w_isem[NBOX], w_co[LL];
    __shared__ int   w_slut[NSTUFF + NBOX];

    const int t = threadIdx.x;
    const int tile = blockIdx.x;
    const int tx0 = (tile % TILES_X) * TW;
    const int ty0 = (tile / TILES_X) * TH;

    const int x = tx0 + (t & 63);           // this thread's single pixel
    const int y = ty0 + (t >> 6);
    const int p = y * WW + x;

    // All 10 channels upfront (independent scalar loads, one latency round)
    const float* semb = sem + (size_t)b * NCLS * NPIX;
    float s[NCLS];
    #pragma unroll
    for (int c = 0; c < NCLS; ++c)
        s[c] = semb[(size_t)c * NPIX + p];

    for (int i = t; i < NHIST; i += NTHR) sh_cnt[i] = 0;

    // wave 0: per-box setup + in-register tile cull
    if (t < 64) {
        bool flag = false;
        if (t < NBOX) {
            const float* bbp = bbx + ((size_t)b * NBOX + t) * 4;
            float y0f = bbp[0], x0f = bbp[1], y1f = bbp[2], x1f = bbp[3];
            int y0 = (int)floorf(y0f), x0 = (int)floorf(x0f);
            int y1 = (int)floorf(y1f), x1 = (int)floorf(x1f);
            int yme = min(y1 + 1, HH), xme = min(x1 + 1, WW);
            int yie = (int)rintf(y1f) + 1, xie = (int)rintf(x1f) + 1;
            sh_y0[t] = y0;  sh_x0[t] = x0;
            sh_yme[t] = yme; sh_xme[t] = xme;
            sh_yie[t] = yie; sh_xie[t] = xie;
            sh_y0f[t] = (float)y0; sh_x0f[t] = (float)x0;
            float hh = (float)max(y1 - y0 + 1, 1);
            float ww = (float)max(x1 - x0 + 1, 1);
            sh_sy[t] = 28.0f / hh;  sh_sx[t] = 28.0f / ww;
            int c = cls[b * NBOX + t];
            sh_cls[t] = c;
            sh_moff[t] = (((b * NBOX + t) * NTHING) + c) * (RR * RR);
            int uy = max(yme, yie), ux = max(xme, xie);
            flag = (y0 < ty0 + TH) && (uy > ty0) && (x0 < tx0 + TW) && (ux > tx0);
        }
        unsigned long long m = __ballot(flag);
        if (flag) {
            int pos = __popcll(m & (((unsigned long long)1 << t) - 1ull));
            sh_list[pos] = t;
        }
        if (t == 0) sh_nbox = __popcll(m);
    }
    __syncthreads();

    const int nb = sh_nbox;
    const float yf = (float)y, xf = (float)x;

    // ---- depth-2 pipeline state: FLAT NAMED SCALARS (no aggregates) ----
    int   a_n = 0, a_c = 0;     bool a_inm = false, a_ini = false;
    float a_wy = 0.f, a_wx = 0.f, a_m00 = 0.f, a_m01 = 0.f, a_m10 = 0.f, a_m11 = 0.f;
    int   b_n = 0, b_c = 0;     bool b_inm = false, b_ini = false;
    float b_wy = 0.f, b_wx = 0.f, b_m00 = 0.f, b_m01 = 0.f, b_m10 = 0.f, b_m11 = 0.f;

#define STAGE_A(P, jj)                                                         \
    {                                                                          \
        const int n_ = sh_list[jj];                                            \
        P##_n = n_;                                                            \
        P##_c = sh_cls[n_];                                                    \
        P##_inm = (y >= max(sh_y0[n_], 0)) & (y < sh_yme[n_]) &                \
                  (x >= max(sh_x0[n_], 0)) & (x < sh_xme[n_]);                 \
        P##_ini = (y >= sh_y0[n_]) & (y < sh_yie[n_]) &                        \
                  (x >= sh_x0[n_]) & (x < sh_xie[n_]);                         \
        float sy_ = __fsub_rn(__fmul_rn(__fadd_rn(__fsub_rn(yf, sh_y0f[n_]), 0.5f), sh_sy[n_]), 0.5f); \
        sy_ = fminf(fmaxf(sy_, 0.0f), 27.0f);                                  \
        int ylo_ = (int)sy_;                                                   \
        int yhi_ = min(ylo_ + 1, RR - 1);                                      \
        P##_wy = __fsub_rn(sy_, (float)ylo_);                                  \
        float sx_ = __fsub_rn(__fmul_rn(__fadd_rn(__fsub_rn(xf, sh_x0f[n_]), 0.5f), sh_sx[n_]), 0.5f); \
        sx_ = fminf(fmaxf(sx_, 0.0f), 27.0f);                                  \
        int xlo_ = (int)sx_;                                                   \
        int xhi_ = min(xlo_ + 1, RR - 1);                                      \
        P##_wx = __fsub_rn(sx_, (float)xlo_);                                  \
        const float* m_ = roi + sh_moff[n_];                                   \
        P##_m00 = m_[ylo_ * RR + xlo_]; P##_m01 = m_[ylo_ * RR + xhi_];        \
        P##_m10 = m_[yhi_ * RR + xlo_]; P##_m11 = m_[yhi_ * RR + xhi_];        \
    }

#define STAGE_B(P)                                                             \
    {                                                                          \
        const int n_ = P##_n;                                                  \
        if (n_ > prev + 1 && bv < 0.0f) { bv = -0.0f; bi = NSTUFF + prev + 1; }\
        float v_;                                                              \
        if (P##_inm | P##_ini) {                                               \
            float pm_ = NEGV;                                                  \
            if (P##_inm) {                                                     \
                float omy_ = __fsub_rn(1.0f, P##_wy), omx_ = __fsub_rn(1.0f, P##_wx); \
                float rl_ = __fadd_rn(__fmul_rn(P##_m00, omy_), __fmul_rn(P##_m10, P##_wy)); \
                float rh_ = __fadd_rn(__fmul_rn(P##_m01, omy_), __fmul_rn(P##_m11, P##_wy)); \
                pm_ = __fadd_rn(__fmul_rn(rl_, omx_), __fmul_rn(rh_, P##_wx)); \
            }                                                                  \
            float pi_ = NEGV;                                                  \
            if (P##_ini) {                                                     \
                int c_ = P##_c;                                                \
                pi_ = (c_ == 0) ? s[6] : (c_ == 1) ? s[7] : (c_ == 2) ? s[8] : s[9]; \
            }                                                                  \
            v_ = __fmul_rn(__fadd_rn(sigmoidf_(pi_), sigmoidf_(pm_)), __fadd_rn(pi_, pm_)); \
        } else {                                                               \
            v_ = -0.0f;                                                        \
        }                                                                      \
        if (v_ > bv) { bv = v_; bi = NSTUFF + n_; }                            \
        prev = n_;                                                             \
    }

    if (nb > 0) STAGE_A(a, 0);

    // sem_pred: full 10-channel argmax, first-occurrence ties
    float sb = s[0]; int sp = 0;
    #pragma unroll
    for (int c = 1; c < NCLS; ++c) if (s[c] > sb) { sb = s[c]; sp = c; }

    // stuff argmax
    float bv = s[0]; int bi = 0;
    #pragma unroll
    for (int c = 1; c < NSTUFF; ++c) if (s[c] > bv) { bv = s[c]; bi = c; }

    int prev = -1;
    for (int jb = 0; jb < nb; ++jb) {
        if (jb + 1 < nb) STAGE_A(b, jb + 1);
        STAGE_B(a);
        a_n = b_n; a_c = b_c; a_inm = b_inm; a_ini = b_ini;
        a_wy = b_wy; a_wx = b_wx;
        a_m00 = b_m00; a_m01 = b_m01; a_m10 = b_m10; a_m11 = b_m11;
    }
    if (prev < NBOX - 1 && bv < 0.0f) { bi = NSTUFF + prev + 1; }

#undef STAGE_A
#undef STAGE_B

    pred8[(size_t)b * NPIX + p] = (unsigned char)bi;

    // histogram: ballot-aggregate stuff bins; scatter-atomic instance pixels
    const int lane = t & 63;
    #pragma unroll
    for (int sc = 0; sc < NSTUFF; ++sc) {
        int c = __popcll(__ballot(bi == sc));
        if (lane == 0 && c) atomicAdd(&sh_cnt[NBOX * NCLS + sc], c);
    }
    if (bi >= NSTUFF) atomicAdd(&sh_cnt[(bi - NSTUFF) * NCLS + sp], 1);

    __syncthreads();

    // ---- write full local hist to partials (overwrite; no zeroing) ----
    int* myp = partials + ((size_t)b * NTILES + tile) * NHP;
    for (int i = t; i < NHIST; i += NTHR) myp[i] = sh_cnt[i];
    __threadfence();            // make this block's stores device-visible
    __syncthreads();
    // ticket lives in out's po_iscrowd[b][0]; (old+1)%NTILES==0 picks exactly
    // one winner per batch for ANY starting value (poison/replay-safe).
    if (t == 0)
        sh_old = atomicAdd(out + (size_t)BB * NPIX + BB * LL + b * LL, 1);
    __syncthreads();

    if (((unsigned)(sh_old + 1)) % NTILES == 0) {
        __threadfence();        // acquire: other blocks' partials visible
        if (t < NHIST) {
            int a = 0;
            const int* pb = partials + (size_t)b * NTILES * NHP + t;
            #pragma unroll 4
            for (int j = 0; j < NTILES; ++j) a += pb[(size_t)j * NHP];
            sh_cnt[t] = a;      // reuse as the global histogram
        }
        __syncthreads();

        // LUT compute (ported intact from k_relabel's wave-0 path)
        int  ssum = 0, mj = 0, semv = 0, idx = -1;
        bool pres = false, ts = false;
        if (t < 64) {
            if (t < NSTUFF) w_sh[t] = sh_cnt[NBOX * NCLS + t];
            if (t < NBOX)  { w_ih[t] = 0; w_isem[t] = 255; }
            if (t < LL)      w_co[t] = 255;

            if (t < NBOX) {
                int m = sh_cnt[t * NCLS]; mj = 0; ssum = m;
                #pragma unroll
                for (int i = 1; i < NCLS; ++i) {
                    int ci = sh_cnt[t * NCLS + i];
                    ssum += ci;
                    if (ci > m) { m = ci; mj = i; }
                }
                pres = ssum > 0;
                int thing = cls[b * NBOX + t] + NSTUFF;
                ts = pres && (mj != thing) && (2 * m >= ssum) && (mj < NSTUFF);
                semv = ts ? mj : thing;
            }
            unsigned long long pm = __ballot(pres);
            idx = __popcll(pm & (((unsigned long long)2 << t) - 1ull)) - 1;

            if (t < NBOX && pres &&  ts) atomicAdd(&w_sh[mj], ssum);
            if (t < NBOX && pres && !ts) { atomicAdd(&w_ih[idx], ssum); w_isem[idx] = semv; }
        }
        __syncthreads();
        if (t < 64) {
            bool spres = (t < NSTUFF) && (w_sh[t] > 0);
            unsigned long long sm = __ballot(spres);
            const int nst = __popcll(sm);
            bool ipres = (t < NBOX) && (w_ih[t] > 0);
            unsigned long long im = __ballot(ipres);

            auto srank = [&](int c) { return __popcll(sm & (((unsigned long long)2 << c) - 1ull)) - 1; };
            auto irank = [&](int j) { return __popcll(im & (((unsigned long long)2 << j) - 1ull)) - 1; };

            if (t < NSTUFF) w_slut[t] = 1 + srank(t);
            if (t < NBOX) {
                int q2 = idx < 0 ? 0 : idx;
                w_slut[NSTUFF + t] = ts ? (1 + srank(mj)) : (1 + nst + irank(q2));
            }
            if (spres) w_co[1 + srank(t)] = t;
            if (ipres) w_co[1 + nst + irank(t)] = w_isem[t];
        }
        __syncthreads();
        // publish LUT (77 ints) to ws; visible to k_relabel via dispatch edge
        int* lutb = lutws + b * 128;
        if (t < NSTUFF + NBOX) lutb[t] = w_slut[t];
        if (t < LL) lutb[64 + t] = w_co[t];
    }
}

// ---------------------------------------------------------------------------
// K2: pure remap. Loads the precomputed LUT (77 ints, L2-hit) and remaps
// pred bytes -> out. Pred load issued before the LUT barrier. Block (0,b)
// also writes po_cls / po_iscrowd (overwriting the ticket slot with 0).
// ---------------------------------------------------------------------------
__global__ __launch_bounds__(256) void k_relabel(
    const int*    __restrict__ lutws,
    const uchar4* __restrict__ pred8,
    int*          __restrict__ out)
{
    const int b = blockIdx.y;
    const int t = threadIdx.x;
    __shared__ int slut[NSTUFF + NBOX];
    __shared__ int l_co[LL];

    // issue the pred load first (independent of the LUT)
    const size_t q = (size_t)b * (NPIX / 4) + (size_t)blockIdx.x * 256 + t;
    const uchar4 v = pred8[q];

    if (t < NSTUFF + NBOX) slut[t] = lutws[b * 128 + t];
    if (t < LL)            l_co[t] = lutws[b * 128 + 64 + t];
    __syncthreads();

    int4 o;
    o.x = slut[v.x];
    o.y = slut[v.y];
    o.z = slut[v.z];
    o.w = slut[v.w];
    ((int4*)out)[q] = o;

    if (blockIdx.x == 0 && t < LL) {
        int* ocls = out + (size_t)BB * NPIX + b * LL;
        int* ocrd = out + (size_t)BB * NPIX + BB * LL + b * LL;
        ocls[t] = l_co[t];
        ocrd[t] = 0;        // also resets the ticket slot
    }
}

extern "C" void kernel_launch(void* const* d_in, const int* in_sizes, int n_in,
                              void* d_out, int out_size, void* d_ws, size_t ws_size,
                              hipStream_t stream) {
    (void)in_sizes; (void)n_in; (void)out_size; (void)ws_size;
    const float* sem = (const float*)d_in[0];
    const float* roi = (const float*)d_in[1];
    const float* bbx = (const float*)d_in[2];
    const int*   cls = (const int*)d_in[3];
    int* out = (int*)d_out;

    // ws layout: partials [BB][528][NHP] ints | lut [BB][128] ints | pred8
    int* partials = (int*)d_ws;
    int* lutws = partials + (size_t)BB * NTILES * NHP;
    unsigned char* pred8 = (unsigned char*)(lutws + BB * 128);

    dim3 g1(NTILES, BB);
    k_fuse<<<g1, NTHR, 0, stream>>>(sem, roi, bbx, cls, pred8, partials, lutws, out);
    dim3 g2(NPIX / 1024, BB);   // 528 blocks/batch, 256 thr x 4 px
    k_relabel<<<g2, 256, 0, stream>>>(lutws, (const uchar4*)pred8, out);
}

// Round 10
// 102.666 us; speedup vs baseline: 3.8284x; 3.8284x over previous
//
#include <hip/hip_runtime.h>
#include <math.h>

#define NSTUFF 6
#define NCLS   10          // N_STUFF + N_THING
#define NBOX   32
#define NTHING 4
#define RR     28
#define HH     768
#define WW     704
#define NPIX   (HH * WW)   // 540672
#define BB     2
#define LL     (1 + NSTUFF + NBOX)   // 39
#define NEGV   (-100.0f)

// Tile 64x16, 1056 blocks. History:
//   R6:  256 thr / 4 px = 108.6 us end-to-end
//   R7:  4224 blocks REGRESSED (per-block fixed cost)
//   R8/R10: box-outer restructure REGRESSED — VALU never the bottleneck
//   R12: 512 thr / 2 px = 105.2 (WIN); R13: 1024 thr / 1 px = 104.0 (WIN)
//   R14: pipeline via struct/lambdas REGRESSED (promote-alloca -> LDS)
//   R15: pipeline via named scalars = 103.8 (BEST)
//   R16: memset removal via last-block reduction + __threadfence REGRESSED
//        393 us: device-scope fences per block force per-XCD L2
//        writeback/invalidate on CDNA4 (L2s not cross-coherent) — ~0.3 us
//        x 1056 blocks, VALUBusy 3%. NEVER per-block device fences here.
//   R17 (this): exact revert to R15/R8 (verified 103.8).
#define TW 64
#define TH 16
#define TILES_X (WW / TW)            // 11
#define TILES_Y (HH / TH)            // 48
#define NTILES  (TILES_X * TILES_Y)  // 528 per batch
#define NHIST   (NBOX * NCLS + NSTUFF)
#define NTHR    1024

__device__ __forceinline__ float sigmoidf_(float x) {
    return 1.0f / (1.0f + expf(-x));
}

// ---------------------------------------------------------------------------
// K1: tiled fused logits + argmax + histograms. 1 px/thread; 10 independent
// scalar sem loads (64x4B coalesced), one latency round. Per-tile box cull
// in-register by wave 0. Box loop is a depth-2 software pipeline in named
// scalar registers: the 4 roi loads of box j+1 are issued (unconditional,
// clamped in-bounds) before box j's sigmoid/merge, hiding the L2 round.
// Sequential-argmax semantics preserved via the gap rule (skipped boxes
// contribute exactly -0.0f; only the first box of a skipped run can win, and
// only while bv < 0; -0.0f < 0.0f is false so a claim happens at most once
// per run).
// ---------------------------------------------------------------------------
__global__ __launch_bounds__(NTHR, 4) void k_fuse(
    const float* __restrict__ sem,   // [B][10][H][W]
    const float* __restrict__ roi,   // [B][32][4][28][28]
    const float* __restrict__ bbx,   // [B][32][4]
    const int*   __restrict__ cls,   // [B][32]
    unsigned char* __restrict__ pred8, // ws region, [B][H][W] bytes
    int*         __restrict__ counts,
    int*         __restrict__ stuffh)
{
    const int b = blockIdx.y;
    __shared__ int   sh_y0[NBOX], sh_x0[NBOX], sh_yme[NBOX], sh_xme[NBOX];
    __shared__ int   sh_yie[NBOX], sh_xie[NBOX], sh_moff[NBOX], sh_cls[NBOX];
    __shared__ float sh_y0f[NBOX], sh_x0f[NBOX], sh_sy[NBOX], sh_sx[NBOX];
    __shared__ int   sh_list[NBOX];
    __shared__ int   sh_nbox;
    __shared__ int   sh_cnt[NHIST];

    const int t = threadIdx.x;
    const int tile = blockIdx.x;
    const int tx0 = (tile % TILES_X) * TW;
    const int ty0 = (tile / TILES_X) * TH;

    const int x = tx0 + (t & 63);           // this thread's single pixel
    const int y = ty0 + (t >> 6);
    const int p = y * WW + x;

    // All 10 channels upfront (independent scalar loads, one latency round)
    const float* semb = sem + (size_t)b * NCLS * NPIX;
    float s[NCLS];
    #pragma unroll
    for (int c = 0; c < NCLS; ++c)
        s[c] = semb[(size_t)c * NPIX + p];

    for (int i = t; i < NHIST; i += NTHR) sh_cnt[i] = 0;

    // wave 0: per-box setup + in-register tile cull
    if (t < 64) {
        bool flag = false;
        if (t < NBOX) {
            const float* bbp = bbx + ((size_t)b * NBOX + t) * 4;
            float y0f = bbp[0], x0f = bbp[1], y1f = bbp[2], x1f = bbp[3];
            int y0 = (int)floorf(y0f), x0 = (int)floorf(x0f);
            int y1 = (int)floorf(y1f), x1 = (int)floorf(x1f);
            int yme = min(y1 + 1, HH), xme = min(x1 + 1, WW);
            int yie = (int)rintf(y1f) + 1, xie = (int)rintf(x1f) + 1;
            sh_y0[t] = y0;  sh_x0[t] = x0;
            sh_yme[t] = yme; sh_xme[t] = xme;
            sh_yie[t] = yie; sh_xie[t] = xie;
            sh_y0f[t] = (float)y0; sh_x0f[t] = (float)x0;
            float hh = (float)max(y1 - y0 + 1, 1);
            float ww = (float)max(x1 - x0 + 1, 1);
            sh_sy[t] = 28.0f / hh;  sh_sx[t] = 28.0f / ww;
            int c = cls[b * NBOX + t];
            sh_cls[t] = c;
            sh_moff[t] = (((b * NBOX + t) * NTHING) + c) * (RR * RR);
            int uy = max(yme, yie), ux = max(xme, xie);
            flag = (y0 < ty0 + TH) && (uy > ty0) && (x0 < tx0 + TW) && (ux > tx0);
        }
        unsigned long long m = __ballot(flag);
        if (flag) {
            int pos = __popcll(m & (((unsigned long long)1 << t) - 1ull));
            sh_list[pos] = t;
        }
        if (t == 0) sh_nbox = __popcll(m);
    }
    __syncthreads();

    const int nb = sh_nbox;
    const float yf = (float)y, xf = (float)x;

    // ---- depth-2 pipeline state: FLAT NAMED SCALARS (no aggregates) ----
    int   a_n = 0, a_c = 0;     bool a_inm = false, a_ini = false;
    float a_wy = 0.f, a_wx = 0.f, a_m00 = 0.f, a_m01 = 0.f, a_m10 = 0.f, a_m11 = 0.f;
    int   b_n = 0, b_c = 0;     bool b_inm = false, b_ini = false;
    float b_wy = 0.f, b_wx = 0.f, b_m00 = 0.f, b_m01 = 0.f, b_m10 = 0.f, b_m11 = 0.f;

    // STAGE_A(dst, jj): params + coords + issue 4 roi loads (unconditional —
    // coords clamp to [0,27] so addresses are always in-bounds; lanes outside
    // the box hit the same L2-resident mask lines).
#define STAGE_A(P, jj)                                                         \
    {                                                                          \
        const int n_ = sh_list[jj];                                            \
        P##_n = n_;                                                            \
        P##_c = sh_cls[n_];                                                    \
        P##_inm = (y >= max(sh_y0[n_], 0)) & (y < sh_yme[n_]) &                \
                  (x >= max(sh_x0[n_], 0)) & (x < sh_xme[n_]);                 \
        P##_ini = (y >= sh_y0[n_]) & (y < sh_yie[n_]) &                        \
                  (x >= sh_x0[n_]) & (x < sh_xie[n_]);                         \
        float sy_ = __fsub_rn(__fmul_rn(__fadd_rn(__fsub_rn(yf, sh_y0f[n_]), 0.5f), sh_sy[n_]), 0.5f); \
        sy_ = fminf(fmaxf(sy_, 0.0f), 27.0f);                                  \
        int ylo_ = (int)sy_;                                                   \
        int yhi_ = min(ylo_ + 1, RR - 1);                                      \
        P##_wy = __fsub_rn(sy_, (float)ylo_);                                  \
        float sx_ = __fsub_rn(__fmul_rn(__fadd_rn(__fsub_rn(xf, sh_x0f[n_]), 0.5f), sh_sx[n_]), 0.5f); \
        sx_ = fminf(fmaxf(sx_, 0.0f), 27.0f);                                  \
        int xlo_ = (int)sx_;                                                   \
        int xhi_ = min(xlo_ + 1, RR - 1);                                      \
        P##_wx = __fsub_rn(sx_, (float)xlo_);                                  \
        const float* m_ = roi + sh_moff[n_];                                   \
        P##_m00 = m_[ylo_ * RR + xlo_]; P##_m01 = m_[ylo_ * RR + xhi_];        \
        P##_m10 = m_[yhi_ * RR + xlo_]; P##_m11 = m_[yhi_ * RR + xhi_];        \
    }

    // STAGE_B(src): gap-claim + bilinear + fused-logit + merge (exact FP
    // order of the verified kernel in the selected paths).
#define STAGE_B(P)                                                             \
    {                                                                          \
        const int n_ = P##_n;                                                  \
        if (n_ > prev + 1 && bv < 0.0f) { bv = -0.0f; bi = NSTUFF + prev + 1; }\
        float v_;                                                              \
        if (P##_inm | P##_ini) {                                               \
            float pm_ = NEGV;                                                  \
            if (P##_inm) {                                                     \
                float omy_ = __fsub_rn(1.0f, P##_wy), omx_ = __fsub_rn(1.0f, P##_wx); \
                float rl_ = __fadd_rn(__fmul_rn(P##_m00, omy_), __fmul_rn(P##_m10, P##_wy)); \
                float rh_ = __fadd_rn(__fmul_rn(P##_m01, omy_), __fmul_rn(P##_m11, P##_wy)); \
                pm_ = __fadd_rn(__fmul_rn(rl_, omx_), __fmul_rn(rh_, P##_wx)); \
            }                                                                  \
            float pi_ = NEGV;                                                  \
            if (P##_ini) {                                                     \
                int c_ = P##_c;                                                \
                pi_ = (c_ == 0) ? s[6] : (c_ == 1) ? s[7] : (c_ == 2) ? s[8] : s[9]; \
            }                                                                  \
            v_ = __fmul_rn(__fadd_rn(sigmoidf_(pi_), sigmoidf_(pm_)), __fadd_rn(pi_, pm_)); \
        } else {                                                               \
            v_ = -0.0f;                                                        \
        }                                                                      \
        if (v_ > bv) { bv = v_; bi = NSTUFF + n_; }                            \
        prev = n_;                                                             \
    }

    // pipeline prologue: issue box 0's roi loads BEFORE the sem argmax so
    // their L2 round overlaps the tail of the sem HBM wait.
    if (nb > 0) STAGE_A(a, 0);

    // sem_pred: full 10-channel argmax, first-occurrence ties
    float sb = s[0]; int sp = 0;
    #pragma unroll
    for (int c = 1; c < NCLS; ++c) if (s[c] > sb) { sb = s[c]; sp = c; }

    // stuff argmax
    float bv = s[0]; int bi = 0;
    #pragma unroll
    for (int c = 1; c < NSTUFF; ++c) if (s[c] > bv) { bv = s[c]; bi = c; }

    int prev = -1;
    for (int jb = 0; jb < nb; ++jb) {
        if (jb + 1 < nb) STAGE_A(b, jb + 1);    // issue next box's loads
        STAGE_B(a);                             // compute current box
        // rotate: scalar copies stay in VGPRs
        a_n = b_n; a_c = b_c; a_inm = b_inm; a_ini = b_ini;
        a_wy = b_wy; a_wx = b_wx;
        a_m00 = b_m00; a_m01 = b_m01; a_m10 = b_m10; a_m11 = b_m11;
    }
    if (prev < NBOX - 1 && bv < 0.0f) { bi = NSTUFF + prev + 1; }

#undef STAGE_A
#undef STAGE_B

    pred8[(size_t)b * NPIX + p] = (unsigned char)bi;

    // histogram: ballot-aggregate stuff bins; scatter-atomic instance pixels
    const int lane = t & 63;
    #pragma unroll
    for (int sc = 0; sc < NSTUFF; ++sc) {
        int c = __popcll(__ballot(bi == sc));
        if (lane == 0 && c) atomicAdd(&sh_cnt[NBOX * NCLS + sc], c);
    }
    if (bi >= NSTUFF) atomicAdd(&sh_cnt[(bi - NSTUFF) * NCLS + sp], 1);

    __syncthreads();
    for (int i = t; i < NHIST; i += NTHR) {
        int v = sh_cnt[i];
        if (v) {
            if (i < NBOX * NCLS) atomicAdd(&counts[b * NBOX * NCLS + i], v);
            else                 atomicAdd(&stuffh[b * NSTUFF + (i - NBOX * NCLS)], v);
        }
    }
}

// ---------------------------------------------------------------------------
// K2: fused label + seam remap. Pred bytes are loaded BEFORE the LUT barrier
// (independent of it) so wave-0's LUT recompute latency is hidden behind the
// global load. Ranks are pure functions of ballot masks. Block (0,b) also
// writes po_cls / po_iscrowd.
// ---------------------------------------------------------------------------
__global__ __launch_bounds__(256) void k_relabel(
    const int*    __restrict__ counts,
    const int*    __restrict__ stuffh,
    const int*    __restrict__ cls,
    const uchar4* __restrict__ pred8,
    int*          __restrict__ out)
{
    const int b = blockIdx.y;
    const int t = threadIdx.x;
    __shared__ int slut[NSTUFF + NBOX];
    __shared__ int l_sh[NSTUFF];
    __shared__ int l_ih[NBOX];
    __shared__ int l_isem[NBOX];
    __shared__ int l_co[LL];

    // issue the pred load first (independent of the LUT)
    const size_t q = (size_t)b * (NPIX / 4) + (size_t)blockIdx.x * 256 + t;
    const uchar4 v = pred8[q];

    int  ssum = 0, mj = 0, semv = 0, idx = -1;
    bool pres = false, ts = false;

    if (t < 64) {
        if (t < NSTUFF) l_sh[t] = stuffh[b * NSTUFF + t];
        if (t < NBOX)  { l_ih[t] = 0; l_isem[t] = 255; }
        if (t < LL)      l_co[t] = 255;

        if (t < NBOX) {
            const int* C = counts + ((size_t)b * NBOX + t) * NCLS;
            int c[NCLS];
            #pragma unroll
            for (int i = 0; i < NCLS; ++i) c[i] = C[i];
            int m = c[0]; mj = 0; ssum = c[0];
            #pragma unroll
            for (int i = 1; i < NCLS; ++i) {
                ssum += c[i];
                if (c[i] > m) { m = c[i]; mj = i; }
            }
            pres = ssum > 0;
            int thing = cls[b * NBOX + t] + NSTUFF;
            ts = pres && (mj != thing) && (2 * m >= ssum) && (mj < NSTUFF);
            semv = ts ? mj : thing;
        }
        unsigned long long pm = __ballot(pres);
        idx = __popcll(pm & (((unsigned long long)2 << t) - 1ull)) - 1;

        if (t < NBOX && pres &&  ts) atomicAdd(&l_sh[mj], ssum);
        if (t < NBOX && pres && !ts) { atomicAdd(&l_ih[idx], ssum); l_isem[idx] = semv; }
    }
    __syncthreads();

    if (t < 64) {
        bool spres = (t < NSTUFF) && (l_sh[t] > 0);
        unsigned long long sm = __ballot(spres);
        const int nst = __popcll(sm);
        bool ipres = (t < NBOX) && (l_ih[t] > 0);
        unsigned long long im = __ballot(ipres);

        auto srank = [&](int c) { return __popcll(sm & (((unsigned long long)2 << c) - 1ull)) - 1; };
        auto irank = [&](int j) { return __popcll(im & (((unsigned long long)2 << j) - 1ull)) - 1; };

        if (t < NSTUFF) slut[t] = 1 + srank(t);
        if (t < NBOX) {
            int q2 = idx < 0 ? 0 : idx;
            slut[NSTUFF + t] = ts ? (1 + srank(mj)) : (1 + nst + irank(q2));
        }
        if (spres) l_co[1 + srank(t)] = t;
        if (ipres) l_co[1 + nst + irank(t)] = l_isem[t];
    }
    __syncthreads();

    int4 o;
    o.x = slut[v.x];
    o.y = slut[v.y];
    o.z = slut[v.z];
    o.w = slut[v.w];
    ((int4*)out)[q] = o;

    if (blockIdx.x == 0 && t < LL) {
        int* ocls = out + (size_t)BB * NPIX + b * LL;
        int* ocrd = out + (size_t)BB * NPIX + BB * LL + b * LL;
        ocls[t] = l_co[t];
        ocrd[t] = 0;
    }
}

extern "C" void kernel_launch(void* const* d_in, const int* in_sizes, int n_in,
                              void* d_out, int out_size, void* d_ws, size_t ws_size,
                              hipStream_t stream) {
    (void)in_sizes; (void)n_in; (void)out_size; (void)ws_size;
    const float* sem = (const float*)d_in[0];
    const float* roi = (const float*)d_in[1];
    const float* bbx = (const float*)d_in[2];
    const int*   cls = (const int*)d_in[3];
    int* out = (int*)d_out;

    int* counts = (int*)d_ws;                        // [B][32][10]
    int* stuffh = counts + BB * NBOX * NCLS;         // [B][6]
    // 652 ints = 2608 B (16B-aligned); pred bytes follow
    unsigned char* pred8 = (unsigned char*)(stuffh + BB * NSTUFF); // [B*NPIX]

    hipMemsetAsync(d_ws, 0, (BB * NBOX * NCLS + BB * NSTUFF) * sizeof(int), stream);

    dim3 g1(NTILES, BB);
    k_fuse<<<g1, NTHR, 0, stream>>>(sem, roi, bbx, cls, pred8, counts, stuffh);
    dim3 g2(NPIX / 1024, BB);   // 528 blocks/batch, 256 thr x 4 px
    k_relabel<<<g2, 256, 0, stream>>>(counts, stuffh, cls, (const uchar4*)pred8, out);
}